// Round 11
// baseline (98.734 us; speedup 1.0000x reference)
//
#include <hip/hip_runtime.h>

typedef __attribute__((ext_vector_type(4))) float f32x4;
typedef __attribute__((ext_vector_type(8))) int v8i;
typedef __attribute__((ext_vector_type(4))) unsigned int u32x4;

#define OFFS 16777216.0f   // 2^24 positivity offset (uint order == float order)
#define INV24 5.9604644775390625e-08f  // 2^-24, exact

static __device__ __forceinline__ unsigned umin2(unsigned a, unsigned b) { return a < b ? a : b; }

// ---------------- Kernel 1: prep ----------------
// codebook fp32 -> (x 2^12) -> fp4 e2m1, stored in 16x16x128 B-fragment order:
// addr = (code>>4)*2048 + kc*1024 + (kq*16 + (code&15))*16 + (kk>>1)
// where k = kc*128 + kq*32 + kk.  norms[code] = sum(dec4^2) in 2^24 units.
__global__ void vq_prep(const float* __restrict__ cb,
                        float* __restrict__ norms,
                        unsigned char* __restrict__ cb4,
                        float* __restrict__ loss_out) {
  if (blockIdx.x == 0 && threadIdx.x == 0) *loss_out = 0.0f;
  const int lane = threadIdx.x & 63;
  const int code = (blockIdx.x * blockDim.x + threadIdx.x) >> 6;  // one wave per code
  const f32x4 v = ((const f32x4*)(cb + (long)code * 256))[lane];  // k = 4*lane..+3
  float n = 0.f;
  unsigned nib[4];
#pragma unroll
  for (int j = 0; j < 4; ++j) {
    float sv = v[j] * 4096.0f;
    float av = fabsf(sv);
    int c = (av >= 0.25f) + (av >= 0.75f) + (av >= 1.25f) + (av >= 1.75f) +
            (av >= 2.5f) + (av >= 3.5f) + (av >= 5.0f);
    float d = (c <= 3) ? 0.5f * (float)c : (c == 4 ? 2.f : (c == 5 ? 3.f : (c == 6 ? 4.f : 6.f)));
    n = __builtin_fmaf(d, d, n);
    nib[j] = (unsigned)c | (sv < 0.f ? 8u : 0u);
  }
  unsigned short u16 = (unsigned short)(nib[0] | (nib[1] << 4) | (nib[2] << 8) | (nib[3] << 12));
  // k0 = 4*lane: kc = lane>>5, kq = (lane>>3)&3, kk = (lane&7)*4 -> byte (lane&7)*2
  const int addr = (code >> 4) * 2048 + (lane >> 5) * 1024 +
                   (((lane >> 3) & 3) * 16 + (code & 15)) * 16 + (lane & 7) * 2;
  *(unsigned short*)(cb4 + addr) = u16;
#pragma unroll
  for (int m = 1; m < 64; m <<= 1) n += __shfl_xor(n, m);
  if (lane == 0) norms[code] = n;
}

// ---------------- Kernel 2: main ----------------
#define BM 128    // rows per block
#define NTHR 512  // 8 waves x 16 rows
#define NSUB 16   // 1024 codes / 64 per subtile

__global__ __launch_bounds__(NTHR, 4)
void vq_main(const float* __restrict__ X,
             const float* __restrict__ CB,
             const float* __restrict__ norms_g,
             const unsigned char* __restrict__ cb4g,
             float* __restrict__ out,
             float* __restrict__ loss_out,
             float lscale) {
  // E double buffer: 2 x (64 codes x 256 k x fp4) = 16 KiB
  __shared__ __attribute__((aligned(16))) unsigned char Eb[2 * 8192];
  __shared__ __attribute__((aligned(16))) float nrmLds[1024];  // 4 KiB

  const int t = threadIdx.x;
  const int lane = t & 63;
  const int wave = t >> 6;  // 0..7 : owns rows 16*wave .. +15
  const int lo16 = lane & 15;
  const int kq = lane >> 4;  // 0..3 : K-quarter within a 128-chunk
  const long rowBase = (long)blockIdx.x * BM;

  // ---- staging: subtile = 8 KiB; 512 thr x 1 x 16B. Linear both sides. ----
  const char* cbB = (const char*)cb4g;
  char* ebBase = (char*)Eb;
#define STAGE_E(ST, BUF)                                                                    \
  __builtin_amdgcn_global_load_lds(                                                         \
      (const __attribute__((address_space(1))) void*)(cbB + (unsigned)(ST)*8192u + t * 16), \
      (__attribute__((address_space(3))) void*)(ebBase + (BUF)*8192 + t * 16), 16, 0, 0);

  STAGE_E(0, 0);  // overlap subtile-0 DMA with A preload

  // ---- norms -> LDS (2^24-scaled fp32) ----
  nrmLds[t] = norms_g[t];
  nrmLds[t + 512] = norms_g[t + 512];

  // ---- A preload: 16 rows/wave, fp32 (nt) -> fp8 in 16x16x128 A-frag order ----
  // lane: row = lo16, k = kc*128 + kq*32 + (int c: 4c..4c+3).  Accumulate ||x||^2.
  float xn = 0.f;
  v8i a[2];
  {
    const float* xrow = X + (rowBase + wave * 16 + lo16) * 256;
#pragma unroll
    for (int kc = 0; kc < 2; ++kc) {
      const f32x4* xb = (const f32x4*)(xrow + kc * 128 + kq * 32);
#pragma unroll
      for (int c = 0; c < 8; ++c) {
        f32x4 q = __builtin_nontemporal_load(xb + c);
#pragma unroll
        for (int j = 0; j < 4; ++j) xn = __builtin_fmaf(q[j], q[j], xn);
        unsigned w = __builtin_amdgcn_cvt_pk_fp8_f32(q[0], q[1], 0, false);
        w = __builtin_amdgcn_cvt_pk_fp8_f32(q[2], q[3], w, true);
        a[kc][c] = (int)w;
      }
    }
  }
  __syncthreads();  // nrmLds visible; drains all prologue vmem (incl. STAGE(0))

  unsigned best[4];
#pragma unroll
  for (int r = 0; r < 4; ++r) best[r] = 0xFFFFFFFFu;

#pragma unroll 2
  for (int st = 0; st < NSUB; ++st) {
    if (st + 1 < NSUB) {
      STAGE_E(st + 1, (st + 1) & 1);
      asm volatile("s_waitcnt vmcnt(1)" ::: "memory");  // stage(st) landed; st+1 in flight
    } else {
      asm volatile("s_waitcnt vmcnt(0)" ::: "memory");
    }
    __builtin_amdgcn_s_barrier();       // stage(st) visible to all waves
    __builtin_amdgcn_sched_barrier(0);  // no ds_read hoists above (rule #18)

    const char* eb = ebBase + (st & 1) * 8192;
    f32x4 acc[4];
#pragma unroll
    for (int n = 0; n < 4; ++n) {
      f32x4 z = {0.f, 0.f, 0.f, 0.f};
      acc[n] = z;
    }
    __builtin_amdgcn_s_setprio(1);
#pragma unroll
    for (int n = 0; n < 4; ++n) {
#pragma unroll
      for (int kc = 0; kc < 2; ++kc) {
        u32x4 q = *(const u32x4*)(eb + (n * 2 + kc) * 1024 + lane * 16);
        v8i b = {(int)q.x, (int)q.y, (int)q.z, (int)q.w,
                 (int)q.x, (int)q.y, (int)q.z, (int)q.w};  // fp4: low 4 regs hold data
        // A = fp8 (cbsz=0), B = fp4 (blgp=4), scales = 1.0 (e8m0 127)
        acc[n] = __builtin_amdgcn_mfma_scale_f32_16x16x128_f8f6f4(a[kc], b, acc[n],
                                                                  0, 4, 0, 127, 0, 127);
      }
    }
    __builtin_amdgcn_s_setprio(0);

    // score'' = 2^24 + ||e''||^2 - 2*2^12*dot'' (always > 0); key = (bits&~1023)|code
#pragma unroll
    for (int n = 0; n < 4; ++n) {
      const float nf = nrmLds[st * 64 + n * 16 + lo16] + OFFS;
      const unsigned code = (unsigned)(st * 64 + n * 16 + lo16);
#pragma unroll
      for (int r = 0; r < 4; ++r) {
        float sv = __builtin_fmaf(-8192.0f, acc[n][r], nf);
        best[r] = umin2(best[r], (__float_as_uint(sv) & 0xFFFFFC00u) | code);
      }
    }

    __builtin_amdgcn_sched_barrier(0);  // keep this subtile's reads/MFMA above barrier B
    __builtin_amdgcn_s_barrier();       // slot st&1 free for stage(st+2)
  }

  // ---- butterfly over the 16 code-lanes: per-row global argmin ----
#pragma unroll
  for (int r = 0; r < 4; ++r) {
#pragma unroll
    for (int msk = 1; msk < 16; msk <<= 1)
      best[r] = umin2(best[r], (unsigned)__shfl_xor((int)best[r], msk));
  }

  // ---- per-wave epilogue: gather 16 rows + analytic loss; no barriers ----
  float ls = xn;
  {
    const f32x4* CBv = (const f32x4*)CB;
    f32x4* Og = (f32x4*)(out + (rowBase + wave * 16) * 256);
#pragma unroll
    for (int rr = 0; rr < 16; ++rr) {
      // C/D layout: row = (lane>>4)*4 + reg  ->  reg = rr&3, src lane group = rr>>2
      unsigned key = (unsigned)__shfl((int)best[rr & 3], (rr >> 2) << 4);
      int code = (int)(key & 1023u);
      // decode midpoint of truncated key -> score_partial = ||e||^2 - 2 x.e
      float scd = __builtin_fmaf(__uint_as_float((key & 0xFFFFFC00u) | 512u), INV24, -1.0f);
      ls += (lane == rr) ? scd : 0.0f;
      f32x4 e = CBv[code * 64 + lane];
      __builtin_nontemporal_store(e, Og + rr * 64 + lane);
    }
  }
#pragma unroll
  for (int m = 1; m < 64; m <<= 1) ls += __shfl_xor(ls, m);
  if (lane == 0) atomicAdd(loss_out, ls * lscale);
}

extern "C" void kernel_launch(void* const* d_in, const int* in_sizes, int n_in,
                              void* d_out, int out_size, void* d_ws, size_t ws_size,
                              hipStream_t stream) {
  const float* X = (const float*)d_in[0];
  const float* CB = (const float*)d_in[1];
  float* out = (float*)d_out;

  const int ND = in_sizes[0];       // 16*4096*256 = 16777216
  const int K = in_sizes[1] / 256;  // 1024
  const int N = ND / 256;           // 65536

  float* ws_norms = (float*)d_ws;                                // K fp32 (4 KiB)
  unsigned char* ws_cb4 = (unsigned char*)((char*)d_ws + 4096);  // K*D/2 fp4 fragments
  float* loss_out = out + (size_t)ND;

  vq_prep<<<K / 4, 256, 0, stream>>>(CB, ws_norms, ws_cb4, loss_out);

  const float lscale = 1.25f / (float)ND;
  vq_main<<<N / BM, NTHR, 0, stream>>>(X, CB, ws_norms, ws_cb4, out, loss_out, lscale);
}

// Round 12
// 63.101 us; speedup vs baseline: 1.5647x; 1.5647x over previous
//
#include <hip/hip_runtime.h>

typedef __attribute__((ext_vector_type(4))) float f32x4;
typedef __attribute__((ext_vector_type(2))) long i64x2;

#define SCALE 262144.0f                 // 2^18 codebook prescale
#define NEG2S -524288.0f                // -2 * SCALE
#define INV_S2 1.4551915228366852e-11f  // 2^-36, exact

static __device__ __forceinline__ unsigned umin2(unsigned a, unsigned b) { return a < b ? a : b; }

// exact e4m3fn decode (bias 7, 3-bit mantissa, denormals at 2^-9)
static __device__ __forceinline__ float dec_e4m3(unsigned b) {
  int e = (b >> 3) & 15, m = b & 7;
  float v = e ? ldexpf((float)(8 + m), e - 10) : ldexpf((float)m, -9);
  return (b & 0x80) ? -v : v;
}

// ---------------- Kernel 1: prep ----------------
// codebook fp32 -> (x SCALE) -> fp8 e4m3, stored PERMUTED: for k = ks*32+hi*8+j,
// byte position = hi*64 + ks*8 + j  (so ds_read_b128 covers 2 k-steps per fragment).
// norms[code] = sum(dec(fp8)^2) fp32 (exact, consistent with MFMA dot).
__global__ void vq_prep(const float* __restrict__ cb,
                        float* __restrict__ norms,
                        unsigned char* __restrict__ cbh,
                        float* __restrict__ loss_out) {
  if (blockIdx.x == 0 && threadIdx.x == 0) *loss_out = 0.0f;
  const int lane = threadIdx.x & 63;
  const int code = (blockIdx.x * blockDim.x + threadIdx.x) >> 6;  // one wave per code
  const f32x4 v = ((const f32x4*)(cb + (long)code * 256))[lane];  // k = 4*lane .. +3
  unsigned w = __builtin_amdgcn_cvt_pk_fp8_f32(v[0] * SCALE, v[1] * SCALE, 0, false);
  w = __builtin_amdgcn_cvt_pk_fp8_f32(v[2] * SCALE, v[3] * SCALE, w, true);
  float n = 0.f;
#pragma unroll
  for (int j = 0; j < 4; ++j) {
    float d = dec_e4m3((w >> (8 * j)) & 0xFFu);
    n = __builtin_fmaf(d, d, n);
  }
  // k0 = 4*lane: ks = lane>>3, hi = (lane>>1)&3, j0 = (lane&1)*4
  const int newpos = ((lane >> 1) & 3) * 64 + (lane >> 3) * 8 + (lane & 1) * 4;
  *(unsigned*)(cbh + (long)code * 256 + newpos) = w;
#pragma unroll
  for (int m = 1; m < 64; m <<= 1) n += __shfl_xor(n, m);
  if (lane == 0) norms[code] = n;
}

// ---------------- Kernel 2: main ----------------
#define BM 128    // rows per block
#define DD 256    // embedding dim
#define NTHR 512  // 8 waves, 16 rows per wave
#define CT 64     // codes per subtile (16 KiB fp8)
#define NSUB 16   // 1024 / CT

__global__ __launch_bounds__(NTHR, 4)
void vq_main(const float* __restrict__ X,
             const float* __restrict__ CB,
             const float* __restrict__ norms_g,
             const unsigned char* __restrict__ cbh,
             float* __restrict__ out,
             float* __restrict__ loss_out,
             float lscale) {
  // E TRIPLE buffer: 3 x (64 codes x 256B fp8) = 48 KiB
  __shared__ __attribute__((aligned(16))) unsigned char Eb[3 * 16384];
  __shared__ __attribute__((aligned(16))) float nrmLds[1024];  // 4 KiB fp32
  __shared__ float wsumX[8];
  __shared__ float wsumS[8];

  const int t = threadIdx.x;
  const int lane = t & 63;
  const int wave = t >> 6;  // 0..7 : owns rows 16*wave .. 16*wave+15
  const int lo16 = lane & 15;
  const int hi = lane >> 4;
  const long rowBase = (long)blockIdx.x * BM;

  // ---- staging: subtile = 16 KiB; 8 waves x 2 chunks x (64 lanes x 16B).
  // LDS dest linear; global SOURCE pre-swizzled with involution o ^= ((o>>8)&7)<<4.
  const char* cbB = (const char*)cbh;
  char* ebBase = (char*)Eb;
#define STAGE_E(ST, BUF)                                                                      \
  {                                                                                           \
    _Pragma("unroll") for (int c = 0; c < 2; ++c) {                                           \
      unsigned o = (unsigned)(wave * 2048 + c * 1024 + lane * 16);                            \
      unsigned src = o ^ ((((o >> 8) & 7u)) << 4);                                            \
      __builtin_amdgcn_global_load_lds(                                                       \
          (const __attribute__((address_space(1))) void*)(cbB + (unsigned)(ST)*16384u + src), \
          (__attribute__((address_space(3))) void*)(ebBase + (unsigned)(BUF)*16384u + wave * 2048 + c * 1024), \
          16, 0, 0);                                                                          \
    }                                                                                         \
  }

  // prologue: fill buffers 0 and 1 (DMA overlaps norms + A preload)
  STAGE_E(0, 0);
  STAGE_E(1, 1);

  // ---- stage norms (fp32) into LDS ----
  nrmLds[t] = norms_g[t];
  nrmLds[t + 512] = norms_g[t + 512];

  // ---- A preload: 16 rows/wave, fp32 global (nt) -> fp8 regs; accumulate ||x||^2 ----
  float xn = 0.f;
  long a[8];
  {
    const f32x4* xr = (const f32x4*)(X + (rowBase + wave * 16 + lo16) * DD);
#pragma unroll
    for (int ks = 0; ks < 8; ++ks) {
      f32x4 v0 = __builtin_nontemporal_load(xr + ks * 8 + hi * 2);
      f32x4 v1 = __builtin_nontemporal_load(xr + ks * 8 + hi * 2 + 1);
#pragma unroll
      for (int j = 0; j < 4; ++j) xn = __builtin_fmaf(v0[j], v0[j], xn);
#pragma unroll
      for (int j = 0; j < 4; ++j) xn = __builtin_fmaf(v1[j], v1[j], xn);
      unsigned w0 = __builtin_amdgcn_cvt_pk_fp8_f32(v0[0], v0[1], 0, false);
      w0 = __builtin_amdgcn_cvt_pk_fp8_f32(v0[2], v0[3], w0, true);
      unsigned w1 = __builtin_amdgcn_cvt_pk_fp8_f32(v1[0], v1[1], 0, false);
      w1 = __builtin_amdgcn_cvt_pk_fp8_f32(v1[2], v1[3], w1, true);
      a[ks] = (long)w0 | ((long)w1 << 32);
    }
  }
  __syncthreads();  // nrmLds visible; drains prologue vmem (buf0+buf1 landed)

  unsigned best[4];
#pragma unroll
  for (int r = 0; r < 4; ++r) best[r] = 0xFFFFFFFFu;

  const unsigned swzl = (unsigned)((lo16 & 7) << 4);
  unsigned nbase[4];
#pragma unroll
  for (int n = 0; n < 4; ++n) nbase[n] = (unsigned)((n * 16 + lo16) * 256) ^ swzl;
  const unsigned hi64 = (unsigned)(hi * 64);

  int rb = 0;  // buffer holding subtile st; write buffer = rb-1 mod 3 = (st+2)%3
  for (int st = 0; st < NSUB; ++st) {
    // wait for stage(st): issued TWO iterations ago; stages st+1,st+2-not-yet -> 2 in flight
    if (st + 1 < NSUB) {
      asm volatile("s_waitcnt vmcnt(2)" ::: "memory");
    } else {
      asm volatile("s_waitcnt vmcnt(0)" ::: "memory");
    }
    __builtin_amdgcn_s_barrier();       // all waves' stage(st) chunks landed & visible
    __builtin_amdgcn_sched_barrier(0);  // pin: nothing moves across (rule #18)

    if (st + 2 < NSUB) {
      const int wb = (rb == 0) ? 2 : rb - 1;  // (st+2) % 3
      STAGE_E(st + 2, wb);
    }

    const char* eb = ebBase + rb * 16384;
    f32x4 acc[4];
#pragma unroll
    for (int n = 0; n < 4; ++n) {
      f32x4 z = {0.f, 0.f, 0.f, 0.f};
      acc[n] = z;
    }
    __builtin_amdgcn_s_setprio(1);
#pragma unroll
    for (int kp = 0; kp < 4; ++kp) {
      const unsigned koff = hi64 + (unsigned)(kp * 16);  // bits 4-7; XOR vs swizzled base
      i64x2 b0 = *(const i64x2*)(eb + (nbase[0] ^ koff));
      i64x2 b1 = *(const i64x2*)(eb + (nbase[1] ^ koff));
      i64x2 b2 = *(const i64x2*)(eb + (nbase[2] ^ koff));
      i64x2 b3 = *(const i64x2*)(eb + (nbase[3] ^ koff));
      acc[0] = __builtin_amdgcn_mfma_f32_16x16x32_fp8_fp8(a[2 * kp], b0.x, acc[0], 0, 0, 0);
      acc[1] = __builtin_amdgcn_mfma_f32_16x16x32_fp8_fp8(a[2 * kp], b1.x, acc[1], 0, 0, 0);
      acc[2] = __builtin_amdgcn_mfma_f32_16x16x32_fp8_fp8(a[2 * kp], b2.x, acc[2], 0, 0, 0);
      acc[3] = __builtin_amdgcn_mfma_f32_16x16x32_fp8_fp8(a[2 * kp], b3.x, acc[3], 0, 0, 0);
      acc[0] = __builtin_amdgcn_mfma_f32_16x16x32_fp8_fp8(a[2 * kp + 1], b0.y, acc[0], 0, 0, 0);
      acc[1] = __builtin_amdgcn_mfma_f32_16x16x32_fp8_fp8(a[2 * kp + 1], b1.y, acc[1], 0, 0, 0);
      acc[2] = __builtin_amdgcn_mfma_f32_16x16x32_fp8_fp8(a[2 * kp + 1], b2.y, acc[2], 0, 0, 0);
      acc[3] = __builtin_amdgcn_mfma_f32_16x16x32_fp8_fp8(a[2 * kp + 1], b3.y, acc[3], 0, 0, 0);
    }
    __builtin_amdgcn_s_setprio(0);

    // score'' = ||e''||^2 - 2*S*(x.e''); pack (monotone & ~1023) | code; running min
#pragma unroll
    for (int n = 0; n < 4; ++n) {
      float nf = nrmLds[st * 64 + n * 16 + lo16];
      unsigned code = (unsigned)(st * 64 + n * 16 + lo16);
#pragma unroll
      for (int r = 0; r < 4; ++r) {
        float sv = __builtin_fmaf(NEG2S, acc[n][r], nf);
        unsigned u = __float_as_uint(sv);
        u = ((int)u < 0) ? ~u : (u | 0x80000000u);
        best[r] = umin2(best[r], (u & 0xFFFFFC00u) | code);
      }
    }

    rb = (rb == 2) ? 0 : rb + 1;
  }

  // ---- butterfly over the 16 code-lanes (lo16): per-row global min ----
#pragma unroll
  for (int r = 0; r < 4; ++r) {
#pragma unroll
    for (int msk = 1; msk < 16; msk <<= 1)
      best[r] = umin2(best[r], (unsigned)__shfl_xor((int)best[r], msk));
  }

  // ---- wave-reduce ||x||^2 partials ----
#pragma unroll
  for (int msk = 1; msk < 64; msk <<= 1) xn += __shfl_xor(xn, msk);
  if (lane == 0) wsumX[wave] = xn;

  __syncthreads();  // Eb free (vmcnt fully drained on last iter)
  unsigned* mg = (unsigned*)Eb;  // [128] final keys
  unsigned* idxArr = mg + BM;    // [128] decoded indices
  if (lo16 == 0) {
#pragma unroll
    for (int r = 0; r < 4; ++r) {
      // C/D layout: row_in_16 = (lane>>4)*4 + r
      mg[wave * 16 + hi * 4 + r] = best[r];
    }
  }
  __syncthreads();
  float sc = 0.f;
  if (t < BM) {
    unsigned e = mg[t];
    idxArr[t] = e & 1023u;
    // decode score'' (midpoint of truncated key), rescale to real units
    unsigned um = (e & 0xFFFFFC00u) | 512u;
    float sr = (um & 0x80000000u) ? __uint_as_float(um & 0x7FFFFFFFu) : __uint_as_float(~um);
    sc = sr * INV_S2;
  }
#pragma unroll
  for (int msk = 1; msk < 64; msk <<= 1) sc += __shfl_xor(sc, msk);
  if (lane == 0) wsumS[wave] = sc;
  __syncthreads();

  // ---- gather fp32 codebook rows -> output (non-temporal store) ----
  {
    const f32x4* CBv = (const f32x4*)CB;
    f32x4* Og = (f32x4*)(out + rowBase * DD);
#pragma unroll 4
    for (int i = 0; i < 16; ++i) {
      int idx = t + NTHR * i;
      int row = idx >> 6, d4 = idx & 63;
      int code = (int)idxArr[row];
      f32x4 e = CBv[code * 64 + d4];
      __builtin_nontemporal_store(e, Og + idx);
    }
  }

  if (t == 0) {
    float tot = 0.f;
#pragma unroll
    for (int w = 0; w < 8; ++w) tot += wsumX[w] + wsumS[w];
    atomicAdd(loss_out, tot * lscale);
  }
}

extern "C" void kernel_launch(void* const* d_in, const int* in_sizes, int n_in,
                              void* d_out, int out_size, void* d_ws, size_t ws_size,
                              hipStream_t stream) {
  const float* X = (const float*)d_in[0];
  const float* CB = (const float*)d_in[1];
  float* out = (float*)d_out;

  const int ND = in_sizes[0];      // 16*4096*256 = 16777216
  const int K = in_sizes[1] / DD;  // 1024
  const int N = ND / DD;           // 65536

  float* ws_norms = (float*)d_ws;                               // K fp32 (4 KiB)
  unsigned char* ws_cb = (unsigned char*)((char*)d_ws + 4096);  // K*D fp8 (permuted)
  float* loss_out = out + (size_t)ND;

  vq_prep<<<K / 4, 256, 0, stream>>>(CB, ws_norms, ws_cb, loss_out);

  const float lscale = 1.25f / (float)ND;
  vq_main<<<N / BM, NTHR, 0, stream>>>(X, CB, ws_norms, ws_cb, out, loss_out, lscale);
}